// Round 3
// baseline (238.898 us; speedup 1.0000x reference)
//
#include <hip/hip_runtime.h>
#include <hip/hip_bf16.h>

#define D 8
#define L 12
#define C 9
#define W 128
#define B 4096
#define EPS 1e-5f

typedef __attribute__((ext_vector_type(8))) short v8s;    // 8 x bf16
typedef __attribute__((ext_vector_type(4))) float v4f;    // 4 x f32 acc
typedef __attribute__((ext_vector_type(16))) float v16f;  // 16 x f32 acc (32x32 MFMA)

// Workspace layout (in floats)
#define OFF_STATS 0        // f32 [18][1024]: c -> sum partial, 9+c -> sumsq partial
#define OFF_B1E   18432    // fp32 [D][32] folded conv1 bias
#define OFF_W1T   18688    // bf16 [D][32 o][10 tap][16 c]  = 40960 halfs
#define OFF_W2T   39168    // bf16 [D][64 o][9 tap][32 ic]  = 147456 halfs
#define OFF_FCWP  112896   // bf16 [D][12 l][1664 k=p*64+o] = 159744 halfs

// Per-wave LDS region (shorts). Serial aliasing within one wave's region:
//   xb  [2 ql][144 row][8]  = 2304
//   h1t [4 icq][73 row][8]  = 2336   (padded 73: conv1 b16 writes bank-free)
//   h2p [1672] + red f32[64][4] @1672 = 2184
#define REGION 2336

__device__ inline unsigned short f2bf(float f) {
    unsigned u = __builtin_bit_cast(unsigned, f);
    u += 0x7FFFu + ((u >> 16) & 1u);                 // round-nearest-even
    return (unsigned short)(u >> 16);
}
__device__ inline unsigned pk2(float a, float b) {
    float2 f2; f2.x = a; f2.y = b;
    __hip_bfloat162 h = __float22bfloat162_rn(f2);   // v_cvt_pk_bf16_f32
    unsigned u; __builtin_memcpy(&u, &h, 4);
    return u;
}

// ---------------------------------------------------------------------------
// Kernel 1:
//   blocks    0..1023 : x scan — BN stats partials -> [18][1024]
//   blocks 1024..1151 : w2t repack, 1 wave per (d,o)  — coalesced reads
//   blocks 1152..1199 : fcwp repack, 2 waves per (d,l) — coalesced reads
//   blocks 1200..1207 : zero d_out (replaces hipMemsetAsync; safe: fully
//                       precedes branch_kernel in the stream)
// NOTE (R0 post-mortem): do NOT materialize a bf16 x-image in workspace —
// per-XCD L2 non-coherence forces an 18.9MB HBM round-trip (WRITE_SIZE 6->72MB)
// and the vmcnt(0) head-of-block wait cost more than the transpose VALU saved.
// ---------------------------------------------------------------------------
__global__ void stats_repack_kernel(const float* __restrict__ x,
                                    const float* __restrict__ w2,
                                    const float* __restrict__ fcw,
                                    float* __restrict__ ws,
                                    float* __restrict__ out) {
    const int t = threadIdx.x;
    __shared__ float red2[4][18];
    if (blockIdx.x < 1024) {
        const int rb = blockIdx.x * 4;               // 4 batch rows per block
        const int w = t & 127, half = t >> 7;        // 2 rows per pass
        float s[9], s2[9];
        #pragma unroll
        for (int c = 0; c < 9; c++) { s[c] = 0.f; s2[c] = 0.f; }
        #pragma unroll
        for (int pass = 0; pass < 2; pass++) {
            const int row = rb + pass * 2 + half;
            const float* xr = x + (size_t)row * 1152 + w;
            #pragma unroll
            for (int c = 0; c < 9; c++) {
                float v = xr[c * 128];
                s[c] += v; s2[c] += v * v;
            }
        }
        // block-reduce 18 partials -> stats[18][1024]
        #pragma unroll
        for (int c = 0; c < 9; c++) {
            #pragma unroll
            for (int off = 32; off >= 1; off >>= 1) {
                s[c]  += __shfl_down(s[c], off);
                s2[c] += __shfl_down(s2[c], off);
            }
        }
        if ((t & 63) == 0) {
            #pragma unroll
            for (int c = 0; c < 9; c++) {
                red2[t >> 6][c] = s[c]; red2[t >> 6][9 + c] = s2[c];
            }
        }
        __syncthreads();
        if (t < 18)
            ws[OFF_STATS + t * 1024 + blockIdx.x] =
                red2[0][t] + red2[1][t] + red2[2][t] + red2[3][t];
    } else if (blockIdx.x < 1152) {
        // w2t: [d][o][ic][tap] -> [d][o][tap][ic]; one wave per (d,o)
        const int g = (blockIdx.x - 1024) * 4 + (t >> 6);   // 0..511
        const int lane = t & 63;
        const int d = g >> 6, o = g & 63;
        const float* src = w2 + (size_t)(d * 64 + o) * 288;
        short* dst = (short*)(ws + OFF_W2T) + (size_t)d * 18432 + o * 288;
        for (int i = lane; i < 288; i += 64) {
            int ic = i / 9, tap = i % 9;
            dst[tap * 32 + ic] = (short)f2bf(src[i]);
        }
    } else if (blockIdx.x < 1200) {
        // fcwp: [d][l][o*26+p] -> [d][l][p*64+o]; two waves per (d,l)
        const int g = (blockIdx.x - 1152) * 4 + (t >> 6);   // 0..191
        const int lane = t & 63;
        const int dl = g >> 1, half = g & 1;
        const float* src = fcw + (size_t)dl * 1664;
        short* dst = (short*)(ws + OFF_FCWP) + (size_t)dl * 1664;
        for (int i = half * 832 + lane; i < half * 832 + 832; i += 64) {
            int o = i / 26, p = i % 26;
            dst[p * 64 + o] = (short)f2bf(src[i]);
        }
    } else {
        // zero d_out (B*L = 49152 floats over 8 blocks)
        const int base = (blockIdx.x - 1200) * 6144;
        float4 z; z.x = z.y = z.z = z.w = 0.f;
        float4* o4 = (float4*)(out + base);
        for (int i = t; i < 1536; i += 256) o4[i] = z;
    }
}

// ---------------------------------------------------------------------------
// Kernel 2: reduce stats partials -> BN scale/shift; fold into conv1 weights.
// Channel reductions parallel across the 4 waves (c = wv, wv+4, wv+8);
// single barrier instead of 18.
// ---------------------------------------------------------------------------
__global__ void fold1_kernel(const float* __restrict__ w1, const float* __restrict__ b1,
                             const float* __restrict__ gamma, const float* __restrict__ beta,
                             float* __restrict__ ws) {
    const int d = blockIdx.x, t = threadIdx.x;
    const int lane = t & 63, wv = t >> 6;
    __shared__ float g[9], bt[9];
    for (int c = wv; c < 9; c += 4) {
        float s = 0.f, s2 = 0.f;
        #pragma unroll
        for (int j = 0; j < 16; j++) {                // coalesced: [18][1024] layout
            s  += ws[OFF_STATS + c * 1024 + lane + 64 * j];
            s2 += ws[OFF_STATS + (9 + c) * 1024 + lane + 64 * j];
        }
        #pragma unroll
        for (int off = 32; off >= 1; off >>= 1) {
            s  += __shfl_down(s, off);
            s2 += __shfl_down(s2, off);
        }
        if (lane == 0) {
            const float N = (float)B * (float)W;
            float m  = s / N;
            float vv = s2 / N - m * m;
            float inv = rsqrtf(vv + EPS);
            float gg = gamma[d * 9 + c] * inv;
            g[c] = gg; bt[c] = beta[d * 9 + c] - gg * m;
        }
    }
    __syncthreads();
    const int o = t >> 3, sub = t & 7;
    short* w1t = (short*)(ws + OFF_W1T);
    short* dst = w1t + (size_t)d * 5120 + o * 160;
    const float* src = w1 + ((size_t)(d * 32 + o)) * 81;
    float bias_part = 0.f;
    for (int tap = sub; tap < 10; tap += 8) {
        for (int c = 0; c < 16; c++) {
            float v = 0.f;
            if (tap < 9 && c < 9) {
                float wv2 = src[c * 9 + tap];
                v = wv2 * g[c];
                bias_part += wv2 * bt[c];
            }
            dst[tap * 16 + c] = (short)f2bf(v);
        }
    }
    bias_part += __shfl_xor(bias_part, 1);
    bias_part += __shfl_xor(bias_part, 2);
    bias_part += __shfl_xor(bias_part, 4);
    if (sub == 0) ws[OFF_B1E + d * 32 + o] = b1[d * 32 + o] + bias_part;
}

// ---------------------------------------------------------------------------
// Kernel 3: the branch. Grid (B/4, D) — one domain per block. Block = 4 batch
// rows, 256 threads (4 waves); wave wv owns batch row wv. Conv pipeline is
// wave-local & barrier-free (region aliasing; all A-reads retire before the
// epilogue's region-aliased writes since every MFMA consuming them precedes
// the stores in program order and myr is wave-private); only FC syncs.
// R3: conv1/conv2 use 32x32x16 MFMA. Same 16KFLOP/instr, same A/B frag reads
// (lane row = l&31, k = (l>>5)*8+j matches the existing xb/h1t/w1t/w2t
// layouts), same 64-AGPR acc budget — but HALF the MFMA instruction count,
// and conv1's K-step (16 = one tap) eliminates the tap-padding entirely:
// 80+144 -> 36+72 MFMA/wave. C/D map: col=lane&31, row=(reg&3)+8*(reg>>2)
// +4*(lane>>5); reg pairs (2j,2j+1) are row-adjacent so maxpool2 stays
// lane-local; pooled p = 4*(j>>1)+(j&1)+2*hi (+16 per m-tile).
// setprio: measured −4.4us (R2) — do not re-add.
// __launch_bounds__(256,4): (256,6) caused catastrophic scratch spills (R8);
// (256,5) + halved acc tiles lost ILP and regressed 164->282 (R12).
// ---------------------------------------------------------------------------
__global__ __launch_bounds__(256, 4)
void branch_kernel(const float* __restrict__ x,
                   const float* __restrict__ b2g,
                   const float* __restrict__ fcb,
                   const float* __restrict__ wts,
                   const float* __restrict__ ws,
                   float* __restrict__ out) {
    const int t = threadIdx.x;
    const int lane = t & 63;
    const int wv = t >> 6;                       // 0..3
    const int d = blockIdx.y;
    const int b0 = blockIdx.x * 4;
    const short* w1t  = (const short*)(ws + OFF_W1T) + (size_t)d * 5120;
    const short* w2t  = (const short*)(ws + OFF_W2T) + (size_t)d * 18432;
    const short* fcwp = (const short*)(ws + OFF_FCWP) + (size_t)d * 12 * 1664;
    const float* b1e  = ws + OFF_B1E + d * 32;

    __shared__ __align__(16) short lds[4 * REGION];   // 18688 B
    short* myr = &lds[wv * REGION];

    const int n = lane & 15, quad = lane >> 4;
    const int m31 = lane & 31, hi = lane >> 5;

    // ---- phase 1: x -> bf16 transposed into own xb (no barrier) ----
    {
        const float* xrow = x + (size_t)(b0 + wv) * 1152;
        #pragma unroll
        for (int rep = 0; rep < 2; rep++) {
            const int w = lane + rep * 64;
            float v[9];
            #pragma unroll
            for (int c = 0; c < 9; c++) v[c] = xrow[c * 128 + w];
            uint4 lo, hivec;
            lo.x = pk2(v[0], v[1]); lo.y = pk2(v[2], v[3]);
            lo.z = pk2(v[4], v[5]); lo.w = pk2(v[6], v[7]);
            hivec.x = (unsigned)(unsigned short)f2bf(v[8]); hivec.y = 0; hivec.z = 0; hivec.w = 0;
            *(uint4*)&myr[(0 * 144 + w) * 8] = lo;
            *(uint4*)&myr[(1 * 144 + w) * 8] = hivec;
        }
        if (lane < 16) {   // zero rows 128..143, both ql planes
            uint4 z; z.x = z.y = z.z = z.w = 0;
            *(uint4*)&myr[(0 * 144 + 128 + lane) * 8] = z;
            *(uint4*)&myr[(1 * 144 + 128 + lane) * 8] = z;
        }
    }

    // ---- phase 2: conv1, 32x32x16. M=128 pos (4 mt), N=32 oc, K=9 taps x16c.
    //      A: xb[(hi*144 + mt*32 + m31 + tap)*8]  (c = hi*8+j)
    //      B: w1t[oc=m31][tap][c = hi*8+j]
    //      -> relu(pool(acc+bias)) parked into h1t[oc>>3][p][oc&7] ----
    {
        const float bias = b1e[m31];
        v16f acc[4];
        #pragma unroll
        for (int mt = 0; mt < 4; mt++) acc[mt] = (v16f)(0.f);
        for (int tap = 0; tap < 9; tap++) {
            v8s Bw = *(const v8s*)&w1t[m31 * 160 + tap * 16 + hi * 8];
            #pragma unroll
            for (int mt = 0; mt < 4; mt++) {
                v8s Af = *(const v8s*)&myr[(hi * 144 + mt * 32 + m31 + tap) * 8];
                acc[mt] = __builtin_amdgcn_mfma_f32_32x32x16_bf16(Af, Bw, acc[mt], 0, 0, 0);
            }
        }
        const int plane = m31 >> 3, col = m31 & 7;
        #pragma unroll
        for (int mt = 0; mt < 4; mt++) {
            #pragma unroll
            for (int j = 0; j < 8; j++) {
                const int p = mt * 16 + 4 * (j >> 1) + (j & 1) + 2 * hi;
                if (p < 60) {
                    float h = fmaxf(fmaxf(acc[mt][2 * j], acc[mt][2 * j + 1]) + bias, 0.f);
                    myr[(plane * 73 + p) * 8 + col] = (short)f2bf(h);
                }
            }
        }
    }

    // ---- phase 3: conv2, 32x32x16. M=64 pos (2 mt), N=64 oc (2 nt),
    //      K=18 steps (tap = s>>1, ic-half = s&1; ic = (s&1)*16 + hi*8 + j).
    //      A: h1t[((s&1)*2+hi)*73 + mt*32 + m31 + tap]
    //      B: w2t[oc][tap][ic]  -> relu(pool(acc+bias)) parked into h2p ----
    {
        const float bias0 = b2g[d * 64 + m31];
        const float bias1 = b2g[d * 64 + 32 + m31];
        v16f acc[2][2];
        #pragma unroll
        for (int mt = 0; mt < 2; mt++)
            #pragma unroll
            for (int nt = 0; nt < 2; nt++) acc[mt][nt] = (v16f)(0.f);
        for (int s = 0; s < 18; s++) {
            const int tap = s >> 1, koff = (s & 1) * 16 + hi * 8;
            v8s Bw0 = *(const v8s*)&w2t[m31 * 288 + tap * 32 + koff];
            v8s Bw1 = *(const v8s*)&w2t[(32 + m31) * 288 + tap * 32 + koff];
            const int aplane = (s & 1) * 2 + hi;
            #pragma unroll
            for (int mt = 0; mt < 2; mt++) {
                v8s Af = *(const v8s*)&myr[(aplane * 73 + mt * 32 + m31 + tap) * 8];
                acc[mt][0] = __builtin_amdgcn_mfma_f32_32x32x16_bf16(Af, Bw0, acc[mt][0], 0, 0, 0);
                acc[mt][1] = __builtin_amdgcn_mfma_f32_32x32x16_bf16(Af, Bw1, acc[mt][1], 0, 0, 0);
            }
        }
        #pragma unroll
        for (int mt = 0; mt < 2; mt++) {
            #pragma unroll
            for (int j = 0; j < 8; j++) {
                const int p = mt * 16 + 4 * (j >> 1) + (j & 1) + 2 * hi;
                if (p < 26) {
                    #pragma unroll
                    for (int nt = 0; nt < 2; nt++) {
                        const int oc = nt * 32 + m31;
                        float h = fmaxf(fmaxf(acc[mt][nt][2 * j], acc[mt][nt][2 * j + 1])
                                        + (nt ? bias1 : bias0), 0.f);
                        const int gs = (oc >> 3) ^ (p & 7);
                        myr[p * 64 + gs * 8 + (oc & 7)] = (short)f2bf(h);
                    }
                }
            }
        }
    }
    __syncthreads();   // h2p of all 4 waves must be visible

    // ---- phase 4: fc via MFMA (cross-wave h2p reads), red in own region ----
    {
        const int lrow = (n < 12) ? n : 0;
        v4f acc = {0.f, 0.f, 0.f, 0.f};
        for (int ks = wv; ks < 52; ks += 4) {
            const int p = ks >> 1;
            const int gs = ((ks & 1) * 4 + quad) ^ (p & 7);   // match writer swizzle
            v8s A  = *(const v8s*)&fcwp[lrow * 1664 + ks * 32 + quad * 8];
            v8s Bf = *(const v8s*)&lds[(n & 3) * REGION + p * 64 + gs * 8];
            acc = __builtin_amdgcn_mfma_f32_16x16x32_bf16(A, Bf, acc, 0, 0, 0);
        }
        float* red = (float*)(myr + 1672);        // own region, above h2p data
        *(float4*)&red[lane * 4] = *(float4*)&acc;
    }
    __syncthreads();
    if (t < 64) {
        float sum[4] = {0.f, 0.f, 0.f, 0.f};
        #pragma unroll
        for (int w = 0; w < 4; w++) {
            const float* redw = (const float*)(&lds[w * REGION + 1672]);
            float4 v = *(const float4*)&redw[lane * 4];
            sum[0] += v.x; sum[1] += v.y; sum[2] += v.z; sum[3] += v.w;
        }
        if (n < 4) {
            const float wgt = wts[(size_t)(b0 + n) * 8 + d];
            #pragma unroll
            for (int r = 0; r < 4; r++) {
                const int l = quad * 4 + r;
                if (l < 12) {
                    float v = fmaxf(sum[r] + fcb[d * 12 + l], 0.f);
                    atomicAdd(&out[(size_t)(b0 + n) * 12 + l], wgt * v);
                }
            }
        }
    }
}

extern "C" void kernel_launch(void* const* d_in, const int* in_sizes, int n_in,
                              void* d_out, int out_size, void* d_ws, size_t ws_size,
                              hipStream_t stream) {
    const float* x       = (const float*)d_in[0];
    const float* weights = (const float*)d_in[1];
    const float* gamma   = (const float*)d_in[2];
    const float* beta    = (const float*)d_in[3];
    const float* w1      = (const float*)d_in[4];
    const float* b1      = (const float*)d_in[5];
    const float* w2      = (const float*)d_in[6];
    const float* b2      = (const float*)d_in[7];
    const float* fcw     = (const float*)d_in[8];
    const float* fcb     = (const float*)d_in[9];
    float* ws  = (float*)d_ws;
    float* out = (float*)d_out;

    stats_repack_kernel<<<dim3(1208), 256, 0, stream>>>(x, w2, fcw, ws, out);
    fold1_kernel<<<dim3(D), 256, 0, stream>>>(w1, b1, gamma, beta, ws);
    branch_kernel<<<dim3(B / 4, D), 256, 0, stream>>>(x, b2, fcb, weights, ws, out);
}

// Round 5
// 222.988 us; speedup vs baseline: 1.0713x; 1.0713x over previous
//
#include <hip/hip_runtime.h>
#include <hip/hip_bf16.h>

#define D 8
#define L 12
#define C 9
#define W 128
#define B 4096
#define EPS 1e-5f

typedef __attribute__((ext_vector_type(8))) short v8s;    // 8 x bf16
typedef __attribute__((ext_vector_type(4))) float v4f;    // 4 x f32 acc

// Workspace layout (in floats)
#define OFF_STATS 0        // f32 [18][1024]: c -> sum partial, 9+c -> sumsq partial
#define OFF_B1E   18432    // fp32 [D][32] folded conv1 bias
#define OFF_W1T   18688    // bf16 [D][32 o][96 kslot] (dense conv1 K; region sized for old 160-slot layout, we use less)
#define OFF_W2T   39168    // bf16 [D][64 o][9 tap][32 ic]  = 147456 halfs
#define OFF_FCWP  112896   // bf16 [D][12 l][1664 k=p*64+o] = 159744 halfs

// Per-wave LDS region (shorts). Serial aliasing within one wave's region:
//   phase1/2: xb plane0 [144 row][8 c0..7] @0 ; c8 tap-strip [144 r][8 j] @1152
//             (strip[r][j] = c8[row r+j]; rows 120..143 pre-zeroed)
//   h1t [4 icq][73 row][8]  = 2336   (padded 73: conv1 b16 writes bank-free)
//   h2p [1672] + red f32[64][4] @1672 = 2184
#define REGION 2336
#define STRIP  1152        // short offset of the c8 tap-strip within a region

__device__ inline unsigned short f2bf(float f) {
    unsigned u = __builtin_bit_cast(unsigned, f);
    u += 0x7FFFu + ((u >> 16) & 1u);                 // round-nearest-even
    return (unsigned short)(u >> 16);
}
__device__ inline unsigned pk2(float a, float b) {
    float2 f2; f2.x = a; f2.y = b;
    __hip_bfloat162 h = __float22bfloat162_rn(f2);   // v_cvt_pk_bf16_f32
    unsigned u; __builtin_memcpy(&u, &h, 4);
    return u;
}

// ---------------------------------------------------------------------------
// Kernel 1:
//   blocks    0..1023 : x scan — BN stats partials -> [18][1024]
//   blocks 1024..1151 : w2t repack, 1 wave per (d,o)  — coalesced reads
//   blocks 1152..1199 : fcwp repack, 2 waves per (d,l) — coalesced reads
//   blocks 1200..1207 : zero d_out (replaces hipMemsetAsync; safe: fully
//                       precedes branch_kernel in the stream)
// NOTE (R0 post-mortem): do NOT materialize a bf16 x-image in workspace —
// per-XCD L2 non-coherence forces an 18.9MB HBM round-trip and the vmcnt(0)
// head-of-block wait costs more than the transpose VALU saved.
// ---------------------------------------------------------------------------
__global__ void stats_repack_kernel(const float* __restrict__ x,
                                    const float* __restrict__ w2,
                                    const float* __restrict__ fcw,
                                    float* __restrict__ ws,
                                    float* __restrict__ out) {
    const int t = threadIdx.x;
    __shared__ float red2[4][18];
    if (blockIdx.x < 1024) {
        const int rb = blockIdx.x * 4;               // 4 batch rows per block
        const int w = t & 127, half = t >> 7;        // 2 rows per pass
        float s[9], s2[9];
        #pragma unroll
        for (int c = 0; c < 9; c++) { s[c] = 0.f; s2[c] = 0.f; }
        #pragma unroll
        for (int pass = 0; pass < 2; pass++) {
            const int row = rb + pass * 2 + half;
            const float* xr = x + (size_t)row * 1152 + w;
            #pragma unroll
            for (int c = 0; c < 9; c++) {
                float v = xr[c * 128];
                s[c] += v; s2[c] += v * v;
            }
        }
        // block-reduce 18 partials -> stats[18][1024]
        #pragma unroll
        for (int c = 0; c < 9; c++) {
            #pragma unroll
            for (int off = 32; off >= 1; off >>= 1) {
                s[c]  += __shfl_down(s[c], off);
                s2[c] += __shfl_down(s2[c], off);
            }
        }
        if ((t & 63) == 0) {
            #pragma unroll
            for (int c = 0; c < 9; c++) {
                red2[t >> 6][c] = s[c]; red2[t >> 6][9 + c] = s2[c];
            }
        }
        __syncthreads();
        if (t < 18)
            ws[OFF_STATS + t * 1024 + blockIdx.x] =
                red2[0][t] + red2[1][t] + red2[2][t] + red2[3][t];
    } else if (blockIdx.x < 1152) {
        // w2t: [d][o][ic][tap] -> [d][o][tap][ic]; one wave per (d,o)
        const int g = (blockIdx.x - 1024) * 4 + (t >> 6);   // 0..511
        const int lane = t & 63;
        const int d = g >> 6, o = g & 63;
        const float* src = w2 + (size_t)(d * 64 + o) * 288;
        short* dst = (short*)(ws + OFF_W2T) + (size_t)d * 18432 + o * 288;
        for (int i = lane; i < 288; i += 64) {
            int ic = i / 9, tap = i % 9;
            dst[tap * 32 + ic] = (short)f2bf(src[i]);
        }
    } else if (blockIdx.x < 1200) {
        // fcwp: [d][l][o*26+p] -> [d][l][p*64+o]; two waves per (d,l)
        const int g = (blockIdx.x - 1152) * 4 + (t >> 6);   // 0..191
        const int lane = t & 63;
        const int dl = g >> 1, half = g & 1;
        const float* src = fcw + (size_t)dl * 1664;
        short* dst = (short*)(ws + OFF_FCWP) + (size_t)dl * 1664;
        for (int i = half * 832 + lane; i < half * 832 + 832; i += 64) {
            int o = i / 26, p = i % 26;
            dst[p * 64 + o] = (short)f2bf(src[i]);
        }
    } else {
        // zero d_out (B*L = 49152 floats over 8 blocks)
        const int base = (blockIdx.x - 1200) * 6144;
        float4 z; z.x = z.y = z.z = z.w = 0.f;
        float4* o4 = (float4*)(out + base);
        for (int i = t; i < 1536; i += 256) o4[i] = z;
    }
}

// ---------------------------------------------------------------------------
// Kernel 2: reduce stats partials -> BN scale/shift; fold into conv1 weights.
// Dense 96-slot conv1 B layout (K = 3 chunks of 32):
//   k < 64 : chunk c=k>>5, quad=(k>>3)&3, j=k&7  -> (tap = c*4+quad, ch = j)
//   k >= 64: quad q=(k>>3)&3, j=k&7:
//            q==0 -> (tap 8, ch j); q==2 -> (tap j, ch 8);
//            q==3 && j==0 -> (tap 8, ch 8); else zero.
// ---------------------------------------------------------------------------
__global__ void fold1_kernel(const float* __restrict__ w1, const float* __restrict__ b1,
                             const float* __restrict__ gamma, const float* __restrict__ beta,
                             float* __restrict__ ws) {
    const int d = blockIdx.x, t = threadIdx.x;
    const int lane = t & 63, wvq = t >> 6;
    __shared__ float g[9], bt[9];
    for (int c = wvq; c < 9; c += 4) {
        float s = 0.f, s2 = 0.f;
        #pragma unroll
        for (int j = 0; j < 16; j++) {                // coalesced: [18][1024] layout
            s  += ws[OFF_STATS + c * 1024 + lane + 64 * j];
            s2 += ws[OFF_STATS + (9 + c) * 1024 + lane + 64 * j];
        }
        #pragma unroll
        for (int off = 32; off >= 1; off >>= 1) {
            s  += __shfl_down(s, off);
            s2 += __shfl_down(s2, off);
        }
        if (lane == 0) {
            const float N = (float)B * (float)W;
            float m  = s / N;
            float vv = s2 / N - m * m;
            float inv = rsqrtf(vv + EPS);
            float gg = gamma[d * 9 + c] * inv;
            g[c] = gg; bt[c] = beta[d * 9 + c] - gg * m;
        }
    }
    __syncthreads();
    const int o = t >> 3, sub = t & 7;
    short* w1t = (short*)(ws + OFF_W1T);
    short* dst = w1t + (size_t)d * 3072 + o * 96;
    const float* src = w1 + ((size_t)(d * 32 + o)) * 81;
    // dense K-slot writes: 12 slots per thread
    for (int k = sub * 12; k < sub * 12 + 12; k++) {
        int tap, ch;
        if (k < 64)      { tap = (k >> 5) * 4 + ((k >> 3) & 3); ch = k & 7; }
        else {
            int q = (k >> 3) & 3, j = k & 7;
            if (q == 0)              { tap = 8; ch = j; }
            else if (q == 2)         { tap = j; ch = 8; }
            else if (q == 3 && j==0) { tap = 8; ch = 8; }
            else                     { tap = -1; ch = 0; }
        }
        float v = (tap >= 0) ? src[ch * 9 + tap] * g[ch] : 0.f;
        dst[k] = (short)f2bf(v);
    }
    // folded bias: sum over the 81 real taps/channels
    float bias_part = 0.f;
    for (int tap = sub; tap < 9; tap += 8) {
        for (int c = 0; c < 9; c++)
            bias_part += src[c * 9 + tap] * bt[c];
    }
    bias_part += __shfl_xor(bias_part, 1);
    bias_part += __shfl_xor(bias_part, 2);
    bias_part += __shfl_xor(bias_part, 4);
    if (sub == 0) ws[OFF_B1E + d * 32 + o] = b1[d * 32 + o] + bias_part;
}

// ---------------------------------------------------------------------------
// Kernel 3: the branch. Grid (B/4, D). Block = 4 batch rows, 256 threads
// (4 waves); wave wv owns batch row wv. Conv pipeline wave-local &
// barrier-free; only FC syncs.
// R4: conv1 K densified 160 -> 96 slots (real K=81): 3 chunks of 32.
//   chunks 0/1: tap = chunk*4+quad, ch = j -> A read = plane0 row (pos+tap),
//               contiguous v8s, SAME gather pattern/cost as before.
//   chunk 2:    quads 0-1: tap 8 (plane0 row pos+8); quads 2-3: ch8 via the
//               tap-strip strip[r][j] = c8[r+j] built in phase 1.
//   => conv1: 48 MFMA / 24 ds_read_b128 (was 80/80); conv2/fc unchanged.
// setprio: measured -4.4us (R2) — do not re-add.
// 32x32 MFMA: measured +8.8us (R3; B row-gather 64 lines/load) — do not.
// __launch_bounds__(256,4): (256,6) spilled (R8); (256,5) regressed (R12).
// ---------------------------------------------------------------------------
__global__ __launch_bounds__(256, 4)
void branch_kernel(const float* __restrict__ x,
                   const float* __restrict__ b2g,
                   const float* __restrict__ fcb,
                   const float* __restrict__ wts,
                   const float* __restrict__ ws,
                   float* __restrict__ out) {
    const int t = threadIdx.x;
    const int lane = t & 63;
    const int wv = t >> 6;                       // 0..3
    const int d = blockIdx.y;
    const int b0 = blockIdx.x * 4;
    const short* w1t  = (const short*)(ws + OFF_W1T) + (size_t)d * 3072;
    const short* w2t  = (const short*)(ws + OFF_W2T) + (size_t)d * 18432;
    const short* fcwp = (const short*)(ws + OFF_FCWP) + (size_t)d * 12 * 1664;
    const float* b1e  = ws + OFF_B1E + d * 32;

    __shared__ __align__(16) short lds[4 * REGION];   // 18688 B
    short* myr = &lds[wv * REGION];

    const int n = lane & 15, quad = lane >> 4;

    // ---- phase 1: x -> bf16 into own region (no barrier; wave-private) ----
    //   plane0 [144 rows][c0..7] @0 ; c8 tap-strip [144 r][8 j] @STRIP
    {
        const float* xrow = x + (size_t)(b0 + wv) * 1152;
        unsigned short c8s[2];
        #pragma unroll
        for (int rep = 0; rep < 2; rep++) {
            const int w = lane + rep * 64;
            float v[9];
            #pragma unroll
            for (int c = 0; c < 9; c++) v[c] = xrow[c * 128 + w];
            uint4 lo;
            lo.x = pk2(v[0], v[1]); lo.y = pk2(v[2], v[3]);
            lo.z = pk2(v[4], v[5]); lo.w = pk2(v[6], v[7]);
            *(uint4*)&myr[w * 8] = lo;
            c8s[rep] = f2bf(v[8]);
        }
        // zero plane0 rows 128..143 and strip rows 120..143 (before strip fill)
        {
            uint4 z; z.x = z.y = z.z = z.w = 0;
            if (lane < 16) *(uint4*)&myr[(128 + lane) * 8] = z;
            if (lane < 24) *(uint4*)&myr[STRIP + (120 + lane) * 8] = z;
        }
        // strip fill: lane w owns c8[w]; write to strip[w-j][j], j=0..7
        #pragma unroll
        for (int rep = 0; rep < 2; rep++) {
            const int w = lane + rep * 64;
            const short c8 = (short)c8s[rep];
            #pragma unroll
            for (int j = 0; j < 8; j++) {
                if (rep == 1 || lane >= j)
                    myr[STRIP + (w - j) * 8 + j] = c8;
            }
        }
    }

    // ---- phase 2: conv1, 16x16x32, dense K=96 (3 chunks). acc[8][2] ----
    {
        const float bias0 = b1e[n], bias1 = b1e[16 + n];
        v4f acc[8][2];
        #pragma unroll
        for (int mt = 0; mt < 8; mt++)
            #pragma unroll
            for (int nt = 0; nt < 2; nt++) { v4f z = {0.f,0.f,0.f,0.f}; acc[mt][nt] = z; }
        #pragma unroll
        for (int ck = 0; ck < 3; ck++) {
            v8s Bw0 = *(const v8s*)&w1t[n * 96 + ck * 32 + quad * 8];
            v8s Bw1 = *(const v8s*)&w1t[(16 + n) * 96 + ck * 32 + quad * 8];
            #pragma unroll
            for (int mt = 0; mt < 8; mt++) {
                const int rowm = mt * 16 + n;
                int aoff;
                if (ck < 2) aoff = (rowm + ck * 4 + quad) * 8;
                else        aoff = (quad < 2) ? (rowm + 8) * 8
                                              : (STRIP + (rowm + (quad - 2) * 8) * 8);
                v8s Af = *(const v8s*)&myr[aoff];
                acc[mt][0] = __builtin_amdgcn_mfma_f32_16x16x32_bf16(Af, Bw0, acc[mt][0], 0, 0, 0);
                acc[mt][1] = __builtin_amdgcn_mfma_f32_16x16x32_bf16(Af, Bw1, acc[mt][1], 0, 0, 0);
            }
        }
        unsigned held[16];
        #pragma unroll
        for (int mt = 0; mt < 8; mt++)
            #pragma unroll
            for (int nt = 0; nt < 2; nt++) {
                const float bb = nt ? bias1 : bias0;
                float h0  = fmaxf(fmaxf(acc[mt][nt][0], acc[mt][nt][1]) + bb, 0.f);
                float h1v = fmaxf(fmaxf(acc[mt][nt][2], acc[mt][nt][3]) + bb, 0.f);
                held[mt * 2 + nt] = pk2(h0, h1v);
            }
        #pragma unroll
        for (int mt = 0; mt < 8; mt++) {
            const int p = mt * 8 + quad * 2;
            #pragma unroll
            for (int nt = 0; nt < 2; nt++) {
                const unsigned pr = held[mt * 2 + nt];
                const int plane = nt * 2 + (n >> 3);     // conv2 ic-chunk
                const int col = n & 7;
                if (p < 60)     myr[(plane * 73 + p) * 8 + col]     = (short)(pr & 0xFFFFu);
                if (p + 1 < 60) myr[(plane * 73 + p + 1) * 8 + col] = (short)(pr >> 16);
            }
        }
    }

    // ---- phase 3: conv2 (A=h1t pos, B=w2 oc). acc[4][4] -> park -> h2p ----
    {
        float biasv[4];
        #pragma unroll
        for (int nt = 0; nt < 4; nt++) biasv[nt] = b2g[d * 64 + nt * 16 + n];
        v4f acc[4][4];
        #pragma unroll
        for (int mt = 0; mt < 4; mt++)
            #pragma unroll
            for (int nt = 0; nt < 4; nt++) { v4f z = {0.f,0.f,0.f,0.f}; acc[mt][nt] = z; }
        for (int tap = 0; tap < 9; tap++) {
            v8s Bw[4];
            #pragma unroll
            for (int nt = 0; nt < 4; nt++)
                Bw[nt] = *(const v8s*)&w2t[(nt * 16 + n) * 288 + tap * 32 + quad * 8];
            #pragma unroll
            for (int mt = 0; mt < 4; mt++) {
                const int row = mt * 16 + n + tap;
                v8s Af = *(const v8s*)&myr[(quad * 73 + row) * 8];
                #pragma unroll
                for (int nt = 0; nt < 4; nt++)
                    acc[mt][nt] = __builtin_amdgcn_mfma_f32_16x16x32_bf16(Af, Bw[nt], acc[mt][nt], 0, 0, 0);
            }
        }
        unsigned held[16];
        #pragma unroll
        for (int mt = 0; mt < 4; mt++)
            #pragma unroll
            for (int nt = 0; nt < 4; nt++) {
                float h0  = fmaxf(fmaxf(acc[mt][nt][0], acc[mt][nt][1]) + biasv[nt], 0.f);
                float h1v = fmaxf(fmaxf(acc[mt][nt][2], acc[mt][nt][3]) + biasv[nt], 0.f);
                held[mt * 4 + nt] = pk2(h0, h1v);
            }
        #pragma unroll
        for (int mt = 0; mt < 4; mt++) {
            const int p = mt * 8 + quad * 2;
            #pragma unroll
            for (int nt = 0; nt < 4; nt++) {
                const unsigned pr = held[mt * 4 + nt];
                const int oc = nt * 16 + n;
                if (p < 26) {
                    const int gs = (oc >> 3) ^ (p & 7);
                    myr[p * 64 + gs * 8 + (oc & 7)] = (short)(pr & 0xFFFFu);
                }
                if (p + 1 < 26) {
                    const int gs = (oc >> 3) ^ ((p + 1) & 7);
                    myr[(p + 1) * 64 + gs * 8 + (oc & 7)] = (short)(pr >> 16);
                }
            }
        }
    }
    __syncthreads();   // h2p of all 4 waves must be visible

    // ---- phase 4: fc via MFMA (cross-wave h2p reads), red in own region ----
    {
        const int lrow = (n < 12) ? n : 0;
        v4f acc = {0.f, 0.f, 0.f, 0.f};
        for (int ks = wv; ks < 52; ks += 4) {
            const int p = ks >> 1;
            const int gs = ((ks & 1) * 4 + quad) ^ (p & 7);   // match writer swizzle
            v8s A  = *(const v8s*)&fcwp[lrow * 1664 + ks * 32 + quad * 8];
            v8s Bf = *(const v8s*)&lds[(n & 3) * REGION + p * 64 + gs * 8];
            acc = __builtin_amdgcn_mfma_f32_16x16x32_bf16(A, Bf, acc, 0, 0, 0);
        }
        float* red = (float*)(myr + 1672);        // own region, above h2p data
        *(float4*)&red[lane * 4] = *(float4*)&acc;
    }
    __syncthreads();
    if (t < 64) {
        float sum[4] = {0.f, 0.f, 0.f, 0.f};
        #pragma unroll
        for (int w = 0; w < 4; w++) {
            const float* redw = (const float*)(&lds[w * REGION + 1672]);
            float4 v = *(const float4*)&redw[lane * 4];
            sum[0] += v.x; sum[1] += v.y; sum[2] += v.z; sum[3] += v.w;
        }
        if (n < 4) {
            const float wgt = wts[(size_t)(b0 + n) * 8 + d];
            #pragma unroll
            for (int r = 0; r < 4; r++) {
                const int l = quad * 4 + r;
                if (l < 12) {
                    float v = fmaxf(sum[r] + fcb[d * 12 + l], 0.f);
                    atomicAdd(&out[(size_t)(b0 + n) * 12 + l], wgt * v);
                }
            }
        }
    }
}

extern "C" void kernel_launch(void* const* d_in, const int* in_sizes, int n_in,
                              void* d_out, int out_size, void* d_ws, size_t ws_size,
                              hipStream_t stream) {
    const float* x       = (const float*)d_in[0];
    const float* weights = (const float*)d_in[1];
    const float* gamma   = (const float*)d_in[2];
    const float* beta    = (const float*)d_in[3];
    const float* w1      = (const float*)d_in[4];
    const float* b1      = (const float*)d_in[5];
    const float* w2      = (const float*)d_in[6];
    const float* b2      = (const float*)d_in[7];
    const float* fcw     = (const float*)d_in[8];
    const float* fcb     = (const float*)d_in[9];
    float* ws  = (float*)d_ws;
    float* out = (float*)d_out;

    stats_repack_kernel<<<dim3(1208), 256, 0, stream>>>(x, w2, fcw, ws, out);
    fold1_kernel<<<dim3(D), 256, 0, stream>>>(w1, b1, gamma, beta, ws);
    branch_kernel<<<dim3(B / 4, D), 256, 0, stream>>>(x, b2, fcb, weights, ws, out);
}